// Round 6
// baseline (141.480 us; speedup 1.0000x reference)
//
#include <hip/hip_runtime.h>

// Fuzzy decoder: num[p,s,o] = max_k min(t0[s,k], t_p[k,o]); out = t + num - t*num.
// S=K=O=512, p in {0,1}. Packed-fp16 semiring GEMM (v_pk_min/v_pk_max), fp32 epilogue.
// R6: LDS-instruction-bound theory. R4C2 per thread (tile 64x32, grid 256), so per k2
// the inner loop is 1 ds_read_b128 (A, 4 rows) + 1 ds_read_b64 (B, 2 cols) per 16 pk ops.
// BK=128 double-buffered LDS, ONE barrier per chunk (staging overlaps compute).
// No d_ws (poison-writeback storm), no atomics.

#define SDIM 512
#define TS 64      // s-tile per block
#define TO 32      // o-tile per block
#define BK 128     // k per chunk
#define BK2 64     // packed k-pairs per chunk
#define NCH 4      // chunks
#define BSTR 36    // padded stride for Bls rows

typedef _Float16 h2 __attribute__((ext_vector_type(2)));

__device__ __forceinline__ h2 pack2(float a, float b) {
    return __builtin_bit_cast(h2, __builtin_amdgcn_cvt_pkrtz(a, b));  // v_cvt_pkrtz_f16_f32
}
__device__ __forceinline__ h2 pmin(h2 a, h2 b) { return __builtin_elementwise_min(a, b); }
__device__ __forceinline__ h2 pmax(h2 a, h2 b) { return __builtin_elementwise_max(a, b); }
__device__ __forceinline__ h2 bch2(unsigned u) { return __builtin_bit_cast(h2, u); }
__device__ __forceinline__ unsigned b32(h2 v) { return __builtin_bit_cast(unsigned, v); }

__global__ __launch_bounds__(256, 2) void fuzzy_compose_kernel(
        const float* __restrict__ t, float* __restrict__ out) {
    // A transposed, col-swizzled: element (k2, s) lives at AlsT[buf][k2][s ^ (((k2>>1)&3)<<3)]
    __shared__ h2 AlsT[2][BK2][TS];
    // B: Bls[buf][k2][o], stride 36
    __shared__ h2 Bls[2][BK2][BSTR];

    const int tid = threadIdx.x;
    const int o0 = blockIdx.x * TO;   // 16 o-tiles
    const int s0 = blockIdx.y * TS;   // 8 s-tiles
    const int p  = blockIdx.z;        // 2 predicates
    const float* __restrict__ Bmat = t + p * (SDIM * SDIM);

    // compute mapping: 4 s-rows x 2 o-cols per thread
    const int ol = (tid & 15) * 2;
    const int sl = (tid >> 4) * 4;

    // A staging: row ar (0..63), k-float4 phase aq (0..3); swizzled col = ar ^ (aq<<3)
    const int ar = tid >> 2, aq = tid & 3;
    const int acol = ar ^ (aq << 3);
    // B staging: 4 rows starting 4*bk2, float4-col bq
    const int bk2 = tid >> 3, bq = tid & 7;

    const float4* __restrict__ Arow =
        reinterpret_cast<const float4*>(t + (s0 + ar) * SDIM);

    h2 acc[4][2];
    #pragma unroll
    for (int j = 0; j < 4; ++j) {
        acc[j][0] = pack2(0.f, 0.f);
        acc[j][1] = pack2(0.f, 0.f);
    }

    float4 fa[8], fb[4];

    // ---- chunk 0 load + store ----
    #pragma unroll
    for (int q = 0; q < 8; ++q) fa[q] = Arow[aq + 4 * q];
    #pragma unroll
    for (int r = 0; r < 4; ++r)
        fb[r] = *reinterpret_cast<const float4*>(Bmat + (4 * bk2 + r) * SDIM + o0 + bq * 4);

    #pragma unroll
    for (int q = 0; q < 8; ++q) {
        const int k2 = (aq + 4 * q) * 2;
        AlsT[0][k2 + 0][acol] = pack2(fa[q].x, fa[q].y);
        AlsT[0][k2 + 1][acol] = pack2(fa[q].z, fa[q].w);
    }
    {
        uint4 u0, u1;
        u0.x = b32(pack2(fb[0].x, fb[1].x)); u0.y = b32(pack2(fb[0].y, fb[1].y));
        u0.z = b32(pack2(fb[0].z, fb[1].z)); u0.w = b32(pack2(fb[0].w, fb[1].w));
        u1.x = b32(pack2(fb[2].x, fb[3].x)); u1.y = b32(pack2(fb[2].y, fb[3].y));
        u1.z = b32(pack2(fb[2].z, fb[3].z)); u1.w = b32(pack2(fb[2].w, fb[3].w));
        *reinterpret_cast<uint4*>(&Bls[0][2 * bk2 + 0][bq * 4]) = u0;
        *reinterpret_cast<uint4*>(&Bls[0][2 * bk2 + 1][bq * 4]) = u1;
    }

    for (int c = 0; c < NCH; ++c) {
        __syncthreads();   // buf[c&1] ready; buf[(c+1)&1] free (readers done last iter)

        // global prefetch of chunk c+1 (latency hidden under compute below)
        if (c + 1 < NCH) {
            const int kf4 = (c + 1) * (BK / 4);
            #pragma unroll
            for (int q = 0; q < 8; ++q) fa[q] = Arow[kf4 + aq + 4 * q];
            #pragma unroll
            for (int r = 0; r < 4; ++r)
                fb[r] = *reinterpret_cast<const float4*>(
                    Bmat + ((c + 1) * BK + 4 * bk2 + r) * SDIM + o0 + bq * 4);
        }

        // compute: per k2 = 1 b128 (A) + 1 b64 (B) + 16 pk instrs
        const int buf = c & 1;
        #pragma unroll
        for (int k2 = 0; k2 < BK2; ++k2) {
            const int swz = ((k2 >> 1) & 3) << 3;
            const uint4 ua = *reinterpret_cast<const uint4*>(&AlsT[buf][k2][sl ^ swz]);
            const uint2 ub = *reinterpret_cast<const uint2*>(&Bls[buf][k2][ol]);
            const h2 b0 = bch2(ub.x), b1 = bch2(ub.y);
            const h2 a0 = bch2(ua.x), a1 = bch2(ua.y), a2 = bch2(ua.z), a3 = bch2(ua.w);
            acc[0][0] = pmax(acc[0][0], pmin(a0, b0));
            acc[0][1] = pmax(acc[0][1], pmin(a0, b1));
            acc[1][0] = pmax(acc[1][0], pmin(a1, b0));
            acc[1][1] = pmax(acc[1][1], pmin(a1, b1));
            acc[2][0] = pmax(acc[2][0], pmin(a2, b0));
            acc[2][1] = pmax(acc[2][1], pmin(a2, b1));
            acc[3][0] = pmax(acc[3][0], pmin(a3, b0));
            acc[3][1] = pmax(acc[3][1], pmin(a3, b1));
        }

        // stage chunk c+1 into the other buffer (no barrier needed before next iter's top)
        if (c + 1 < NCH) {
            const int nb = (c + 1) & 1;
            #pragma unroll
            for (int q = 0; q < 8; ++q) {
                const int k2 = (aq + 4 * q) * 2;
                AlsT[nb][k2 + 0][acol] = pack2(fa[q].x, fa[q].y);
                AlsT[nb][k2 + 1][acol] = pack2(fa[q].z, fa[q].w);
            }
            uint4 u0, u1;
            u0.x = b32(pack2(fb[0].x, fb[1].x)); u0.y = b32(pack2(fb[0].y, fb[1].y));
            u0.z = b32(pack2(fb[0].z, fb[1].z)); u0.w = b32(pack2(fb[0].w, fb[1].w));
            u1.x = b32(pack2(fb[2].x, fb[3].x)); u1.y = b32(pack2(fb[2].y, fb[3].y));
            u1.z = b32(pack2(fb[2].z, fb[3].z)); u1.w = b32(pack2(fb[2].w, fb[3].w));
            *reinterpret_cast<uint4*>(&Bls[nb][2 * bk2 + 0][bq * 4]) = u0;
            *reinterpret_cast<uint4*>(&Bls[nb][2 * bk2 + 1][bq * 4]) = u1;
        }
    }

    // fused epilogue: num = max of packed k-pair; out = t + num - t*num (fp32)
    const float* __restrict__ tp = t + p * (SDIM * SDIM);
    float* __restrict__ op = out + p * (SDIM * SDIM);
    #pragma unroll
    for (int j = 0; j < 4; ++j) {
        const int row = s0 + sl + j;
        const float2 tv = *reinterpret_cast<const float2*>(tp + row * SDIM + o0 + ol);
        const float n0 = fmaxf((float)acc[j][0][0], (float)acc[j][0][1]);
        const float n1 = fmaxf((float)acc[j][1][0], (float)acc[j][1][1]);
        float2 r;
        r.x = tv.x + n0 - tv.x * n0;
        r.y = tv.y + n1 - tv.y * n1;
        *reinterpret_cast<float2*>(op + row * SDIM + o0 + ol) = r;
    }
}

extern "C" void kernel_launch(void* const* d_in, const int* in_sizes, int n_in,
                              void* d_out, int out_size, void* d_ws, size_t ws_size,
                              hipStream_t stream) {
    const float* t = (const float*)d_in[0];
    float* out = (float*)d_out;
    dim3 grid(SDIM / TO, SDIM / TS, 2);   // 16 x 8 x 2 = 256 blocks (1/CU)
    fuzzy_compose_kernel<<<grid, 256, 0, stream>>>(t, out);
}

// Round 7
// 95.275 us; speedup vs baseline: 1.4850x; 1.4850x over previous
//
#include <hip/hip_runtime.h>

// Fuzzy decoder: num[p,s,o] = max_k min(t0[s,k], t_p[k,o]); out = t + num - t*num.
// S=K=O=512, p in {0,1}. Packed-fp16 semiring GEMM (v_pk_min/v_pk_max), fp32 epilogue.
// R7: R5's safe skeleton (grid 512, 2 blocks/CU, single-buffer LDS ~17KB, no d_ws)
// + BK=128 (8 barriers, global latency fully hidden under 32-step compute)
// + k-pair uint2 layout: one ds_read_b128 (A) + one ds_read_b128 (B) per TWO k2 slices.

#define SDIM 512
#define TS 32      // s-tile per block
#define TO 32      // o-tile per block
#define BK 128     // k per chunk
#define NKQ 32     // k-quads (4 k) per chunk
#define NCH 4      // chunks
#define RSTR 34    // padded row stride in uint2 (272 B: 16B-aligned, bank-spread)

typedef _Float16 h2 __attribute__((ext_vector_type(2)));

__device__ __forceinline__ h2 pack2(float a, float b) {
    return __builtin_bit_cast(h2, __builtin_amdgcn_cvt_pkrtz(a, b));  // v_cvt_pkrtz_f16_f32
}
__device__ __forceinline__ h2 pmin(h2 a, h2 b) { return __builtin_elementwise_min(a, b); }
__device__ __forceinline__ h2 pmax(h2 a, h2 b) { return __builtin_elementwise_max(a, b); }
__device__ __forceinline__ h2 bch2(unsigned u) { return __builtin_bit_cast(h2, u); }
__device__ __forceinline__ unsigned b32(h2 v) { return __builtin_bit_cast(unsigned, v); }

__global__ __launch_bounds__(256, 2) void fuzzy_compose_kernel(
        const float* __restrict__ t, float* __restrict__ out) {
    // A2[kq][s] = uint2{ h2(k=4kq,4kq+1), h2(k=4kq+2,4kq+3) } for s-row s
    __shared__ uint2 A2[NKQ][RSTR];
    // B2[kq][o] = uint2{ h2(..), h2(..) } same k-quad for o-col o
    __shared__ uint2 B2[NKQ][RSTR];

    const int tid = threadIdx.x;
    const int o0 = blockIdx.x * TO;   // 16 o-tiles
    const int s0 = blockIdx.y * TS;   // 16 s-tiles
    const int p  = blockIdx.z;        // 2 predicates
    const float* __restrict__ Bmat = t + p * (SDIM * SDIM);

    // compute mapping: 2 s-rows x 2 o-cols per thread
    const int ol = (tid & 15) * 2;
    const int sl = (tid >> 4) * 2;

    // A staging: row ar (0..31), float4-phase aq (0..7): f = aq + 8q, q=0..3
    const int ar = tid >> 3, aq = tid & 7;
    // B staging: k-quad bkq (0..31), float4-col bq (0..7)
    const int bkq = tid >> 3, bq = tid & 7;

    const float4* __restrict__ Arow =
        reinterpret_cast<const float4*>(t + (s0 + ar) * SDIM);

    // acc[s][o] = {even-k2 h2, odd-k2 h2}
    h2 acc[2][2][2];
    #pragma unroll
    for (int j = 0; j < 2; ++j)
        #pragma unroll
        for (int i = 0; i < 2; ++i) {
            acc[j][i][0] = pack2(0.f, 0.f);
            acc[j][i][1] = pack2(0.f, 0.f);
        }

    float4 fa[4], fb[4];
    // prologue: load chunk 0
    #pragma unroll
    for (int q = 0; q < 4; ++q) fa[q] = Arow[aq + 8 * q];
    #pragma unroll
    for (int r = 0; r < 4; ++r)
        fb[r] = *reinterpret_cast<const float4*>(Bmat + (4 * bkq + r) * SDIM + o0 + bq * 4);

    for (int c = 0; c < NCH; ++c) {
        // ---- stage chunk c (regs -> LDS) ----
        #pragma unroll
        for (int q = 0; q < 4; ++q) {
            const int f = aq + 8 * q;     // k-quad index
            uint2 u;
            u.x = b32(pack2(fa[q].x, fa[q].y));
            u.y = b32(pack2(fa[q].z, fa[q].w));
            A2[f][ar] = u;                // b64 store, banks (4f+2ar)%32: conflict-free
        }
        {
            uint4 u01, u23;
            u01.x = b32(pack2(fb[0].x, fb[1].x)); u01.y = b32(pack2(fb[2].x, fb[3].x));
            u01.z = b32(pack2(fb[0].y, fb[1].y)); u01.w = b32(pack2(fb[2].y, fb[3].y));
            u23.x = b32(pack2(fb[0].z, fb[1].z)); u23.y = b32(pack2(fb[2].z, fb[3].z));
            u23.z = b32(pack2(fb[0].w, fb[1].w)); u23.w = b32(pack2(fb[2].w, fb[3].w));
            *reinterpret_cast<uint4*>(&B2[bkq][bq * 4 + 0]) = u01;   // 16B-aligned
            *reinterpret_cast<uint4*>(&B2[bkq][bq * 4 + 2]) = u23;
        }

        // issue global loads for chunk c+1 (latency hidden under barrier + compute)
        if (c + 1 < NCH) {
            const int kf4 = (c + 1) * (BK / 4);
            #pragma unroll
            for (int q = 0; q < 4; ++q) fa[q] = Arow[kf4 + aq + 8 * q];
            #pragma unroll
            for (int r = 0; r < 4; ++r)
                fb[r] = *reinterpret_cast<const float4*>(
                    Bmat + ((c + 1) * BK + 4 * bkq + r) * SDIM + o0 + bq * 4);
        }

        __syncthreads();   // staged tile visible to all

        // ---- compute: per kq = 1 b128 (A: 2s x 2k2) + 1 b128 (B: 2o x 2k2) + 16 pk ----
        #pragma unroll
        for (int kq = 0; kq < NKQ; ++kq) {
            const uint4 ua = *reinterpret_cast<const uint4*>(&A2[kq][sl]);
            const uint4 ub = *reinterpret_cast<const uint4*>(&B2[kq][ol]);
            const h2 a0e = bch2(ua.x), a0o = bch2(ua.y);
            const h2 a1e = bch2(ua.z), a1o = bch2(ua.w);
            const h2 b0e = bch2(ub.x), b0o = bch2(ub.y);
            const h2 b1e = bch2(ub.z), b1o = bch2(ub.w);
            acc[0][0][0] = pmax(acc[0][0][0], pmin(a0e, b0e));
            acc[0][0][1] = pmax(acc[0][0][1], pmin(a0o, b0o));
            acc[0][1][0] = pmax(acc[0][1][0], pmin(a0e, b1e));
            acc[0][1][1] = pmax(acc[0][1][1], pmin(a0o, b1o));
            acc[1][0][0] = pmax(acc[1][0][0], pmin(a1e, b0e));
            acc[1][0][1] = pmax(acc[1][0][1], pmin(a1o, b0o));
            acc[1][1][0] = pmax(acc[1][1][0], pmin(a1e, b1e));
            acc[1][1][1] = pmax(acc[1][1][1], pmin(a1o, b1o));
        }

        if (c + 1 < NCH) __syncthreads();   // readers done before next stage overwrites
    }

    // fused epilogue: num = max over the 4 fp16 partial maxes; out = t + num - t*num (fp32)
    const float* __restrict__ tp = t + p * (SDIM * SDIM);
    float* __restrict__ op = out + p * (SDIM * SDIM);
    #pragma unroll
    for (int j = 0; j < 2; ++j) {
        const int row = s0 + sl + j;
        const float2 tv = *reinterpret_cast<const float2*>(tp + row * SDIM + o0 + ol);
        const h2 m0 = pmax(acc[j][0][0], acc[j][0][1]);
        const h2 m1 = pmax(acc[j][1][0], acc[j][1][1]);
        const float n0 = fmaxf((float)m0[0], (float)m0[1]);
        const float n1 = fmaxf((float)m1[0], (float)m1[1]);
        float2 r;
        r.x = tv.x + n0 - tv.x * n0;
        r.y = tv.y + n1 - tv.y * n1;
        *reinterpret_cast<float2*>(op + row * SDIM + o0 + ol) = r;
    }
}

extern "C" void kernel_launch(void* const* d_in, const int* in_sizes, int n_in,
                              void* d_out, int out_size, void* d_ws, size_t ws_size,
                              hipStream_t stream) {
    const float* t = (const float*)d_in[0];
    float* out = (float*)d_out;
    dim3 grid(SDIM / TO, SDIM / TS, 2);   // 16 x 16 x 2 = 512 blocks (2/CU)
    fuzzy_compose_kernel<<<grid, 256, 0, stream>>>(t, out);
}